// Round 1
// baseline (111.862 us; speedup 1.0000x reference)
//
#include <hip/hip_runtime.h>
#include <float.h>

#define CHUNK 2048
#define BLOCK 256
#define RPT   2              // ref points per thread
#define TILE  (BLOCK * RPT)  // 512 ref points per block

__global__ void zero_out_kernel(float* out) { out[0] = 0.0f; }

// One block: one (direction, chunk, ref-tile) triple.
//   dir 0: src = pc1 (output_pc), ref = pc2 (gt_pc)   -> dist1 terms
//   dir 1: src = pc2,             ref = pc1           -> dist2 terms
// For each ref point p in the tile, computes min over the 2048-point chunk of
//   ||p - q||^2 = (|q|^2 - 2 p.q) + |p|^2
// then block-reduces the sum of mins and atomicAdds (sum * 1/(nchunks*m)).
__global__ __launch_bounds__(BLOCK, 2)
void chamfer_kernel(const float* __restrict__ p1, const float* __restrict__ p2,
                    int n1, int n2, float* __restrict__ out)
{
    __shared__ float4 q[CHUNK];
    __shared__ float wsum[BLOCK / 64];

    const int dir = blockIdx.z;
    const float* __restrict__ src = dir ? p2 : p1;
    const float* __restrict__ ref = dir ? p1 : p2;
    const int nsrc = dir ? n2 : n1;
    const int m    = dir ? n1 : n2;
    const int nchunks = nsrc / CHUNK;

    const int c = blockIdx.y;
    const int tile0 = blockIdx.x * TILE;
    if (c >= nchunks || tile0 >= m) return;   // uniform over the block

    const float scale = 1.0f / ((float)nchunks * (float)m);

    // ---- stage chunk into LDS as (x, y, z, |q|^2) ----
    const float* __restrict__ chunk = src + (size_t)c * CHUNK * 3;
    for (int k = threadIdx.x; k < CHUNK; k += BLOCK) {
        float x = chunk[3 * k + 0];
        float y = chunk[3 * k + 1];
        float z = chunk[3 * k + 2];
        q[k] = make_float4(x, y, z, fmaf(x, x, fmaf(y, y, z * z)));
    }
    __syncthreads();

    // ---- load this thread's ref points ----
    float px[RPT], py[RPT], pz[RPT], sp[RPT];
    float mna[RPT], mnb[RPT];
    bool valid[RPT];
#pragma unroll
    for (int r = 0; r < RPT; ++r) {
        int j = tile0 + threadIdx.x + r * BLOCK;
        valid[r] = (j < m);
        int jj = valid[r] ? j : 0;
        float x = ref[3 * jj + 0];
        float y = ref[3 * jj + 1];
        float z = ref[3 * jj + 2];
        px[r] = -2.0f * x;
        py[r] = -2.0f * y;
        pz[r] = -2.0f * z;
        sp[r] = fmaf(x, x, fmaf(y, y, z * z));
        mna[r] = FLT_MAX;   // even-k min chain
        mnb[r] = FLT_MAX;   // odd-k min chain (breaks serial dependency)
    }

    // ---- main loop: 3 FMA + 1 min per distance ----
#pragma unroll 2
    for (int k = 0; k < CHUNK; k += 2) {
        float4 qa = q[k];
        float4 qb = q[k + 1];
#pragma unroll
        for (int r = 0; r < RPT; ++r) {
            float ta = fmaf(px[r], qa.x, fmaf(py[r], qa.y, fmaf(pz[r], qa.z, qa.w)));
            float tb = fmaf(px[r], qb.x, fmaf(py[r], qb.y, fmaf(pz[r], qb.z, qb.w)));
            mna[r] = fminf(mna[r], ta);
            mnb[r] = fminf(mnb[r], tb);
        }
    }

    // ---- per-thread sum of completed mins ----
    float sum = 0.0f;
#pragma unroll
    for (int r = 0; r < RPT; ++r) {
        if (valid[r]) {
            float d = fminf(mna[r], mnb[r]) + sp[r];
            sum += fmaxf(d, 0.0f);  // true distance^2 >= 0; kill rounding negatives
        }
    }

    // ---- block reduction: wave shuffle, then LDS across 4 waves ----
#pragma unroll
    for (int off = 32; off > 0; off >>= 1)
        sum += __shfl_down(sum, off);
    const int lane = threadIdx.x & 63;
    const int wid  = threadIdx.x >> 6;
    if (lane == 0) wsum[wid] = sum;
    __syncthreads();
    if (threadIdx.x == 0) {
        float s = 0.0f;
#pragma unroll
        for (int w = 0; w < BLOCK / 64; ++w) s += wsum[w];
        atomicAdd(out, s * scale);
    }
}

extern "C" void kernel_launch(void* const* d_in, const int* in_sizes, int n_in,
                              void* d_out, int out_size, void* d_ws, size_t ws_size,
                              hipStream_t stream)
{
    const float* p1 = (const float*)d_in[0];  // output_pc, [N,3]
    const float* p2 = (const float*)d_in[1];  // gt_pc,     [M,3]
    float* out = (float*)d_out;

    const int n1 = in_sizes[0] / 3;
    const int n2 = in_sizes[1] / 3;
    const int nc1 = n1 / CHUNK;
    const int nc2 = n2 / CHUNK;
    const int tiles1 = (n2 + TILE - 1) / TILE;  // dir0 ref count = n2
    const int tiles2 = (n1 + TILE - 1) / TILE;  // dir1 ref count = n1

    zero_out_kernel<<<1, 1, 0, stream>>>(out);

    dim3 grid(max(tiles1, tiles2), max(nc1, nc2), 2);
    chamfer_kernel<<<grid, BLOCK, 0, stream>>>(p1, p2, n1, n2, out);
}